// Round 12
// baseline (115.160 us; speedup 1.0000x reference)
//
#include <hip/hip_runtime.h>

static constexpr int NSEQ = 512;
static constexpr int NB = 32;
#define SNEG (-(1 << 30))   // scale of "zero/BIG" lanes; never wins max3

// lane l <- lane (l-1)&63 : DPP wavefront rotate-right-by-1 (gfx9 ctrl 0x13C).
// Must execute at full exec (disabled source lane would yield old=0).
__device__ __forceinline__ float rotup1f(float v) {
  return __int_as_float(__builtin_amdgcn_update_dpp(
      0, __float_as_int(v), 0x13C, 0xf, 0xf, false));
}
__device__ __forceinline__ int rotup1i(int v) {
  return __builtin_amdgcn_update_dpp(0, v, 0x13C, 0xf, 0xf, false);
}
__device__ __forceinline__ float rlane(float v, int idx) {
  return __int_as_float(__builtin_amdgcn_readlane(__float_as_int(v), idx));
}
#define RL4(dst, src, idx)                                                     \
  dst.x = rlane(src.x, idx); dst.y = rlane(src.y, idx);                        \
  dst.z = rlane(src.z, idx); dst.w = rlane(src.w, idx);

// R12 = R11's exact math, ROLLED (I-cache-resident hot loop).
// R7..R11 all measured ~1.2 B/cycle instruction streaming (6.8 cy/inst,
// ILP-independent) -> fully-unrolled ~300KB bodies are I-fetch-bound.
// This version: one epoch body, register-rotated double buffers, rolled
// inner loops; hot body ~650 B, total ~10 KB << 32 KB L1I.
__global__ __launch_bounds__(64) void softdtw_band_kernel(
    const float* __restrict__ x, const float* __restrict__ y,
    float* __restrict__ ws)
{
  const int k = blockIdx.x;
  const int batch = k & (NB - 1);
  const int type = k >> 5;
  const float4* Aq = (const float4*)((type == 2 ? y : x) + (size_t)batch * NSEQ * 4);
  const float4* Bq = (const float4*)((type == 1 ? x : y) + (size_t)batch * NSEQ * 4);

  const int l = threadIdx.x;
  const float K1 = 0.721347520444482f;  // 1/(gamma*ln2), gamma=2
  const float K2 = 1.386294361119891f;  // gamma*ln2

  float4 av    = Aq[l];                    // a[i], i=l
  float4 bseed = Bq[l];                    // b-window for P1 injections
  float4 anc   = Aq[64 + l];               // epoch-0 anext
  float4 bac   = Bq[50 + ((l - 1) & 63)];  // epoch-0 step-A b-buffer
  float4 bbc   = Bq[51 + ((l - 1) & 63)];  // epoch-0 step-B b-buffer
  float4 ann, ban, bbn;                    // next-epoch buffers (reg-rotated)

  float4 bv; RL4(bv, bseed, 0)

  // Seed d=0: E = m0 * 2^fl, m0 in [1,2).
  float EM; int ES;
  float uppm = 0.0f; int upps = SNEG;
  {
    float e0 = av.x - bv.x, e1 = av.y - bv.y, e2 = av.z - bv.z, e3 = av.w - bv.w;
    float dv00 = (e0 * e0 + e1 * e1) + (e2 * e2 + e3 * e3);
    float t = dv00 * (-K1);
    float fl = __builtin_floorf(t);
    float m0 = __builtin_exp2f(t - fl);
    EM = (l == 0) ? m0 : 0.0f;
    ES = (l == 0) ? (int)fl : SNEG;
  }
  int i = l;  // row; invariant i = ilo + ((l-ilo)&63)

// E-space step (verified R9/R11 CORE; full renorm; direct exp2 for dm).
#define CORE(BOT, ACT, BJ)                                                     \
  {                                                                            \
    float rbx_ = rotup1f(bv.x);                                                \
    float rby_ = rotup1f(bv.y);                                                \
    float rbz_ = rotup1f(bv.z);                                                \
    float rbw_ = rotup1f(bv.w);                                                \
    float upm_ = rotup1f(EM);                                                  \
    int   ups_ = rotup1i(ES);                                                  \
    bv.x = (BOT) ? (BJ).x : rbx_;                                              \
    bv.y = (BOT) ? (BJ).y : rby_;                                              \
    bv.z = (BOT) ? (BJ).z : rbz_;                                              \
    bv.w = (BOT) ? (BJ).w : rbw_;                                              \
    float ddx = av.x - bv.x, ddy = av.y - bv.y,                                \
          ddz = av.z - bv.z, ddw = av.w - bv.w;                                \
    float dvv = ddx * ddx;                                                     \
    dvv = __builtin_fmaf(ddy, ddy, dvv);                                       \
    dvv = __builtin_fmaf(ddz, ddz, dvv);                                       \
    dvv = __builtin_fmaf(ddw, ddw, dvv);                                       \
    float dm_ = __builtin_exp2f(dvv * (-K1));                                  \
    int sref_ = max(max(ups_, ES), upps);                                      \
    float pre_ = (__builtin_ldexpf(upm_, ups_ - sref_)                         \
                + __builtin_ldexpf(EM,   ES   - sref_)                         \
                + __builtin_ldexpf(uppm, upps - sref_)) * dm_;                 \
    int pb_ = __float_as_int(pre_);                                            \
    float em_ = __int_as_float((pb_ & 0x007FFFFF) | 0x3F800000);               \
    int sn_ = sref_ + ((pb_ >> 23) - 127);                                     \
    EM = (ACT) ? em_ : 0.0f;                                                   \
    ES = (ACT) ? sn_ : SNEG;                                                   \
    uppm = upm_; upps = ups_;                                                  \
  }

// Two-step macro for d = 51+2m, 52+2m (ilo = m+1). Injections at bot from
// per-lane buffers BA (b[50+m]) / BB (b[51+m]); a[m+64] at top from ANC.
#define MACRO(MM, ANC, BA, BB)                                                 \
  {                                                                            \
    const int m_ = (MM);                                                       \
    i += (i < m_ + 1) ? 64 : 0;                                                \
    const bool bot  = (i == m_ + 1);                                           \
    const bool top  = (i == m_ + 64);                                          \
    const bool actA = (i <= m_ + 50);                                          \
    const bool actB = (i <= m_ + 51);                                          \
    av.x = top ? (ANC).x : av.x;                                               \
    av.y = top ? (ANC).y : av.y;                                               \
    av.z = top ? (ANC).z : av.z;                                               \
    av.w = top ? (ANC).w : av.w;                                               \
    CORE(bot, actA, BA)                                                        \
    CORE(bot, actB, BB)                                                        \
  }

  // ---- P1: d = 1..50 (ilo=0, no jumps; inject b[d] at lane 0) — rolled ----
  {
    const bool bot = (l == 0);
    #pragma clang loop unroll(disable)
    for (int d = 1; d <= 50; ++d) {
      float4 bj; RL4(bj, bseed, d)
      const bool act = (l <= d);
      CORE(bot, act, bj)
    }
  }

  // ---- P2: 7 epochs x 64 macros (d = 51..946) — both loops rolled;
  // double buffers rotate by register copy at epoch end. ----
  #pragma clang loop unroll(disable)
  for (int e = 0; e < 7; ++e) {
    ann = Aq[min(NSEQ - 1, 64 + 64 * (e + 1) + l)];
    ban = Bq[min(NSEQ - 1, 50 + 64 * (e + 1) + ((l - 1) & 63))];
    bbn = Bq[min(NSEQ - 1, 51 + 64 * (e + 1) + ((l - 1) & 63))];
    #pragma clang loop unroll(disable)
    for (int m2 = 0; m2 < 64; ++m2) {
      MACRO(64 * e + m2, anc, bac, bbc)
    }
    anc = ann; bac = ban; bbc = bbn;
  }
  // anc/bac/bbc now hold epoch-7 buffers: anc[l]=A[511] (all lanes),
  // bac[l]=B[min(511,498+((l-1)&63))], bbc[l]=B[min(511,499+((l-1)&63))].

  // ---- P2t: macros m = 448..460 (d = 947..972) — rolled ----
  #pragma clang loop unroll(disable)
  for (int m = 448; m <= 460; ++m) {
    MACRO(m, anc, bac, bbc)
  }
#undef MACRO

  // ---- P3: d = 973..1022 (ilo = d-511; uniform b[511] at bot) — rolled ----
  float4 b511; RL4(b511, bbc, 13)   // bbc[13] = B[499+12] = b[511]
  #pragma clang loop unroll(disable)
  for (int d = 973; d <= 1022; ++d) {
    i += (i < d - 511) ? 64 : 0;
    const bool bot = (i == d - 511);
    const bool act = (i <= NSEQ - 1);
    CORE(bot, act, b511)
  }
#undef CORE

  // R[511,511] on lane 63:  R = -K2 * (log2(m) + s).
  if (l == 63) {
    ws[k] = -K2 * (__builtin_log2f(EM) + (float)ES);
  }
}

__global__ void softdtw_combine_kernel(const float* __restrict__ ws,
                                       float* __restrict__ out) {
  int b = threadIdx.x;
  if (b < NB) out[b] = ws[b] - 0.5f * (ws[NB + b] + ws[2 * NB + b]);
}

extern "C" void kernel_launch(void* const* d_in, const int* in_sizes, int n_in,
                              void* d_out, int out_size, void* d_ws, size_t ws_size,
                              hipStream_t stream) {
  const float* x = (const float*)d_in[0];
  const float* y = (const float*)d_in[1];
  float* ws = (float*)d_ws;
  float* out = (float*)d_out;
  softdtw_band_kernel<<<3 * NB, 64, 0, stream>>>(x, y, ws);
  softdtw_combine_kernel<<<1, 64, 0, stream>>>(ws, out);
}

// Round 13
// 79.762 us; speedup vs baseline: 1.4438x; 1.4438x over previous
//
#include <hip/hip_runtime.h>

static constexpr int NSEQ = 512;
static constexpr int NB = 32;

typedef _Float16 h2v __attribute__((ext_vector_type(2)));

// lane l <- lane (l-1)&63 : DPP wavefront rotate-right-by-1 (gfx9 ctrl 0x13C).
// Must execute at full exec (disabled source lane would yield old=0).
__device__ __forceinline__ float rotup1f(float v) {
  return __int_as_float(__builtin_amdgcn_update_dpp(
      0, __float_as_int(v), 0x13C, 0xf, 0xf, false));
}
__device__ __forceinline__ int rotup1i(int v) {
  return __builtin_amdgcn_update_dpp(0, v, 0x13C, 0xf, 0xf, false);
}
__device__ __forceinline__ int rlanei(int v, int idx) {
  return __builtin_amdgcn_readlane(v, idx);
}
__device__ __forceinline__ h2v BC(int v) { return __builtin_bit_cast(h2v, v); }
__device__ __forceinline__ int packh2(float a, float b) {
  h2v v; v[0] = (_Float16)a; v[1] = (_Float16)b;   // RNE converts
  return __builtin_bit_cast(int, v);
}

#if __has_builtin(__builtin_amdgcn_fdot2)
#define DOT2(a, b, c) __builtin_amdgcn_fdot2((a), (b), (c), false)
#else
__device__ __forceinline__ float dot2f(h2v a, h2v b, float c) {
  return c + (float)a[0] * (float)b[0] + (float)a[1] * (float)b[1];
}
#define DOT2(a, b, c) dot2f((a), (b), (c))
#endif

// R13: plain-E f32 DP + f16 operands. E = 2^{-K1*R} scaled by 2^S (S uniform,
// SGPR): E_new = dm*(Eu+El+Ed) is LINEAR in E -> uniform scale commutes; renorm
// every 16 steps (DPP max-butterfly to lane 63, rescale max to 2^60). BIG/
// inactive = 0.0 (same masking dataflow verified in R9-R12). Operands a,b as
// 2x half2: rotate 2 DPP, inject 2 cndmask, dist = 2 pk_sub + 2 v_dot2_f32_f16.
__global__ __launch_bounds__(64) void softdtw_band_kernel(
    const float* __restrict__ x, const float* __restrict__ y,
    float* __restrict__ ws)
{
  const int k = blockIdx.x;
  const int batch = k & (NB - 1);
  const int type = k >> 5;
  const float4* Aq = (const float4*)((type == 2 ? y : x) + (size_t)batch * NSEQ * 4);
  const float4* Bq = (const float4*)((type == 1 ? x : y) + (size_t)batch * NSEQ * 4);

  const int l = threadIdx.x;
  const float K1 = 0.721347520444482f;  // 1/(gamma*ln2), gamma=2
  const float K2 = 1.386294361119891f;  // gamma*ln2

  float4 af  = Aq[l];
  float4 bf  = Bq[l];
  float4 a0f = Aq[64 + l];
  float4 baf = Bq[50 + ((l - 1) & 63)];
  float4 bbf = Bq[51 + ((l - 1) & 63)];

  int av01 = packh2(af.x, af.y), av23 = packh2(af.z, af.w);
  int bseed01 = packh2(bf.x, bf.y), bseed23 = packh2(bf.z, bf.w);
  int anc01 = packh2(a0f.x, a0f.y), anc23 = packh2(a0f.z, a0f.w);
  int bac01 = packh2(baf.x, baf.y), bac23 = packh2(baf.z, baf.w);
  int bbc01 = packh2(bbf.x, bbf.y), bbc23 = packh2(bbf.z, bbf.w);
  int bv01 = rlanei(bseed01, 0), bv23 = rlanei(bseed23, 0);

  float EM, uppm = 0.0f;
  int S = 0;
  {
    h2v d01 = BC(av01) - BC(bv01);
    h2v d23 = BC(av23) - BC(bv23);
    float dv00 = DOT2(d01, d01, DOT2(d23, d23, 0.0f));
    EM = (l == 0) ? __builtin_exp2f(dv00 * (-K1)) : 0.0f;
  }
  int i = l;  // row; invariant i = ilo + ((l-ilo)&63)

#define CORE(BOT, ACT, BJ01, BJ23)                                             \
  {                                                                            \
    int rb0_ = rotup1i(bv01);                                                  \
    int rb1_ = rotup1i(bv23);                                                  \
    float up_ = rotup1f(EM);                                                   \
    bv01 = (BOT) ? (BJ01) : rb0_;                                              \
    bv23 = (BOT) ? (BJ23) : rb1_;                                              \
    h2v d01_ = BC(av01) - BC(bv01);                                            \
    h2v d23_ = BC(av23) - BC(bv23);                                            \
    float dvv_ = DOT2(d01_, d01_, DOT2(d23_, d23_, 0.0f));                     \
    float dm_ = __builtin_exp2f(dvv_ * (-K1));                                 \
    float pre_ = ((up_ + EM) + uppm) * dm_;                                    \
    EM = (ACT) ? pre_ : 0.0f;                                                  \
    uppm = up_;                                                                \
  }

// Wave-max butterfly (EM >= 0; old=0 is identity), renorm max -> 2^60.
#define RENORM                                                                 \
  {                                                                            \
    float mx_ = EM;                                                            \
    mx_ = fmaxf(mx_, __int_as_float(__builtin_amdgcn_update_dpp(               \
        0, __float_as_int(mx_), 0x111, 0xf, 0xf, false)));                     \
    mx_ = fmaxf(mx_, __int_as_float(__builtin_amdgcn_update_dpp(               \
        0, __float_as_int(mx_), 0x112, 0xf, 0xf, false)));                     \
    mx_ = fmaxf(mx_, __int_as_float(__builtin_amdgcn_update_dpp(               \
        0, __float_as_int(mx_), 0x114, 0xf, 0xf, false)));                     \
    mx_ = fmaxf(mx_, __int_as_float(__builtin_amdgcn_update_dpp(               \
        0, __float_as_int(mx_), 0x118, 0xf, 0xf, false)));                     \
    mx_ = fmaxf(mx_, __int_as_float(__builtin_amdgcn_update_dpp(               \
        0, __float_as_int(mx_), 0x142, 0xf, 0xf, false)));                     \
    mx_ = fmaxf(mx_, __int_as_float(__builtin_amdgcn_update_dpp(               \
        0, __float_as_int(mx_), 0x143, 0xf, 0xf, false)));                     \
    int c_ = 187 - ((__float_as_int(mx_) >> 23) & 0xFF);                       \
    c_ = rlanei(c_, 63);                                                       \
    EM = __builtin_ldexpf(EM, c_);                                             \
    uppm = __builtin_ldexpf(uppm, c_);                                         \
    S += c_;                                                                   \
  }

// Two-step macro for d = 51+2m, 52+2m (ilo = m+1); buffers anc/bac/bbc.
#define MACRO(MM)                                                              \
  {                                                                            \
    const int m_ = (MM);                                                       \
    i += (i < m_ + 1) ? 64 : 0;                                                \
    const bool bot  = (i == m_ + 1);                                           \
    const bool top  = (i == m_ + 64);                                          \
    const bool actA = (i <= m_ + 50);                                          \
    const bool actB = (i <= m_ + 51);                                          \
    av01 = top ? anc01 : av01;                                                 \
    av23 = top ? anc23 : av23;                                                 \
    CORE(bot, actA, bac01, bac23)                                              \
    CORE(bot, actB, bbc01, bbc23)                                              \
  }

  // ---- P1: d = 1..50 (ilo=0; inject b[d] at lane 0); renorm every 16 ----
  {
    const bool bot = (l == 0);
    for (int blk = 0; blk < 3; ++blk) {
      #pragma clang loop unroll(disable)
      for (int t = 1; t <= 16; ++t) {
        const int d = blk * 16 + t;
        int bj01 = rlanei(bseed01, d);
        int bj23 = rlanei(bseed23, d);
        const bool act = (l <= d);
        CORE(bot, act, bj01, bj23)
      }
      RENORM
    }
    #pragma clang loop unroll(disable)
    for (int d = 49; d <= 50; ++d) {
      int bj01 = rlanei(bseed01, d);
      int bj23 = rlanei(bseed23, d);
      const bool act = (l <= d);
      CORE(bot, act, bj01, bj23)
    }
  }

  // ---- P2: 7 epochs x 64 macros (d = 51..946); renorm every 8 macros ----
  #pragma clang loop unroll(disable)
  for (int e = 0; e < 7; ++e) {
    float4 a_  = Aq[min(NSEQ - 1, 64 + 64 * (e + 1) + l)];
    float4 ba_ = Bq[min(NSEQ - 1, 50 + 64 * (e + 1) + ((l - 1) & 63))];
    float4 bb_ = Bq[min(NSEQ - 1, 51 + 64 * (e + 1) + ((l - 1) & 63))];
    #pragma clang loop unroll(disable)
    for (int g = 0; g < 8; ++g) {
      #pragma clang loop unroll(disable)
      for (int m2 = 0; m2 < 8; ++m2) {
        MACRO(64 * e + 8 * g + m2)
      }
      RENORM
    }
    anc01 = packh2(a_.x, a_.y);   anc23 = packh2(a_.z, a_.w);
    bac01 = packh2(ba_.x, ba_.y); bac23 = packh2(ba_.z, ba_.w);
    bbc01 = packh2(bb_.x, bb_.y); bbc23 = packh2(bb_.z, bb_.w);
  }
  // anc/bac/bbc now epoch-7: anc=A[511]; bac[l]=B[min(511,498+((l-1)&63))];
  // bbc[l]=B[min(511,499+((l-1)&63))].

  // ---- P2t: macros m = 448..460 (d = 947..972); tops inactive forever ----
  #pragma clang loop unroll(disable)
  for (int m = 448; m <= 455; ++m) { MACRO(m) }
  RENORM
  #pragma clang loop unroll(disable)
  for (int m = 456; m <= 460; ++m) { MACRO(m) }
#undef MACRO

  // ---- P3: d = 973..1022 (ilo = d-511; uniform b[511] at bot) ----
  {
    int b51101 = rlanei(bbc01, 13);   // bbc[13] = B[511]
    int b51123 = rlanei(bbc23, 13);
    for (int blk = 0; blk < 3; ++blk) {
      #pragma clang loop unroll(disable)
      for (int t = 0; t < 16; ++t) {
        const int d = 973 + blk * 16 + t;
        i += (i < d - 511) ? 64 : 0;
        const bool bot = (i == d - 511);
        const bool act = (i <= NSEQ - 1);
        CORE(bot, act, b51101, b51123)
      }
      RENORM
    }
    #pragma clang loop unroll(disable)
    for (int d = 1021; d <= 1022; ++d) {
      i += (i < d - 511) ? 64 : 0;
      const bool bot = (i == d - 511);
      const bool act = (i <= NSEQ - 1);
      CORE(bot, act, b51101, b51123)
    }
  }
#undef CORE
#undef RENORM

  // R[511,511] on lane 63: stored E = true_E * 2^S -> R = -K2*(log2(EM) - S).
  if (l == 63) {
    ws[k] = -K2 * (__builtin_log2f(EM) - (float)S);
  }
}

__global__ void softdtw_combine_kernel(const float* __restrict__ ws,
                                       float* __restrict__ out) {
  int b = threadIdx.x;
  if (b < NB) out[b] = ws[b] - 0.5f * (ws[NB + b] + ws[2 * NB + b]);
}

extern "C" void kernel_launch(void* const* d_in, const int* in_sizes, int n_in,
                              void* d_out, int out_size, void* d_ws, size_t ws_size,
                              hipStream_t stream) {
  const float* x = (const float*)d_in[0];
  const float* y = (const float*)d_in[1];
  float* ws = (float*)d_ws;
  float* out = (float*)d_out;
  softdtw_band_kernel<<<3 * NB, 64, 0, stream>>>(x, y, ws);
  softdtw_combine_kernel<<<1, 64, 0, stream>>>(ws, out);
}

// Round 15
// 60.627 us; speedup vs baseline: 1.8995x; 1.3156x over previous
//
#include <hip/hip_runtime.h>

static constexpr int NSEQ = 512;
static constexpr int NB = 32;
static constexpr int NPAIR = 511;          // pairs p: diagonals d = 2p+1, 2p+2
static constexpr int LDS_BYTES = 139264;   // 131072 dm + 4096 A2 + 4096 B2

typedef _Float16 h2v __attribute__((ext_vector_type(2)));

// lane l <- lane (l-1)&63 : DPP wave rotate-right-by-1 (verified R5-R13).
// Must execute at full exec.
__device__ __forceinline__ float rotup1f(float v) {
  return __int_as_float(__builtin_amdgcn_update_dpp(
      0, __float_as_int(v), 0x13C, 0xf, 0xf, false));
}
__device__ __forceinline__ int rlanei(int v, int idx) {
  return __builtin_amdgcn_readlane(v, idx);
}
__device__ __forceinline__ h2v BCH(unsigned v) { return __builtin_bit_cast(h2v, v); }
__device__ __forceinline__ unsigned packh2s(float a, float b) {
  h2v v; v[0] = (_Float16)a; v[1] = (_Float16)b;
  return __builtin_bit_cast(unsigned, v);
}
// bf16 round-to-nearest-even (upper 16 bits of f32)
__device__ __forceinline__ unsigned bf16u(float f) {
  unsigned u = __float_as_uint(f);
  u += 0x7FFFu + ((u >> 16) & 1u);
  return u >> 16;
}
#if __has_builtin(__builtin_amdgcn_fdot2)
#define DOT2(a, b, c) __builtin_amdgcn_fdot2((a), (b), (c), false)
#else
__device__ __forceinline__ float dot2f(h2v a, h2v b, float c) {
  return c + (float)a[0] * (float)b[0] + (float)a[1] * (float)b[1];
}
#define DOT2(a, b, c) dot2f((a), (b), (c))
#endif

// R15 = R14 structure (producer/consumer split) with the f16-underflow fix:
// dm table stored as bf16 (RNE) — exp2(-K1*dist²) can no longer flush to 0
// at realistic dist² (R14's inf: f16 dm=0 at the forced final cell).
// Renorm max over BOTH E1,E2 so ldexp can never overflow.
// Stage 1: 16 waves precompute banded dm[d][lane] in LDS (2 diags/u32).
// Stage 2: wave 0 runs the serial DP at ~10 inst/step (6.5 cy/inst law).
__global__ __launch_bounds__(1024) void softdtw_fused(
    const float* __restrict__ x, const float* __restrict__ y,
    float* __restrict__ ws)
{
  extern __shared__ unsigned char lds_raw[];
  unsigned* dmp = (unsigned*)lds_raw;                   // [NPAIR+1][64]
  unsigned* A2  = (unsigned*)(lds_raw + 131072);        // [512][2]
  unsigned* B2  = (unsigned*)(lds_raw + 135168);        // [512][2]

  const int k = blockIdx.x;
  const int batch = k & (NB - 1);
  const int type = k >> 5;
  const float4* Aq = (const float4*)((type == 2 ? y : x) + (size_t)batch * NSEQ * 4);
  const float4* Bq = (const float4*)((type == 1 ? x : y) + (size_t)batch * NSEQ * 4);

  const int tid = threadIdx.x;
  const int l = tid & 63;
  const float SK1 = 0.8493216783f;      // sqrt(1/(2 ln2)); inputs prescaled
  const float K2 = 1.386294361119891f;  // gamma*ln2

  // ---- staging: prescaled f16 a,b into LDS ----
  {
    int idx = tid & 511;
    const float4* src = (tid < 512) ? Aq : Bq;
    float4 v = src[idx];
    unsigned w01 = packh2s(v.x * SK1, v.y * SK1);
    unsigned w23 = packh2s(v.z * SK1, v.w * SK1);
    unsigned* dst = (tid < 512) ? A2 : B2;
    dst[idx * 2] = w01;
    dst[idx * 2 + 1] = w23;
  }
  __syncthreads();

  // ---- stage 1: wave wv computes pairs p = 32*wv .. 32*wv+31 (<=510) ----
  {
    const int wv = tid >> 6;
    #pragma clang loop unroll(disable)
    for (int q = 0; q < 32; ++q) {
      int p = wv * 32 + q;
      if (p > 510) break;
      float dmv0, dmv1;
      #pragma unroll
      for (int s = 0; s < 2; ++s) {
        int d = 2 * p + 1 + s;
        int ilo = max(max(0, d - (NSEQ - 1)), max(0, d - 49) >> 1);
        int tt = (l - ilo) & 63;
        int i0 = ilo + tt;
        int i = min(i0, NSEQ - 1);
        int j = min(max(d - i0, 0), NSEQ - 1);
        uint2 aw = ((const uint2*)A2)[i];
        uint2 bw = ((const uint2*)B2)[j];
        h2v d01 = BCH(aw.x) - BCH(bw.x);
        h2v d23 = BCH(aw.y) - BCH(bw.y);
        float dvv = DOT2(d01, d01, DOT2(d23, d23, 0.0f));
        float dmv = __builtin_exp2f(-dvv);
        if (s == 0) dmv0 = dmv; else dmv1 = dmv;
      }
      dmp[p * 64 + l] = bf16u(dmv0) | (bf16u(dmv1) << 16);   // bf16x2, RNE
    }
  }
  __syncthreads();
  if (tid >= 64) return;

  // ---- stage 2: single-wave DP ----
  int t = l;        // t = i - ilo(d); updated when ilo increments
  int S = 0;
  const unsigned* wp = dmp + l;
  unsigned wc_ = *wp; wp += 64;   // pair 0 prefetched

  // seed d=0: E1 = exp2(-K1*D(0,0)) on lane 0
  float E1, E2 = 0.0f;
  {
    uint2 aw = ((const uint2*)A2)[0];
    uint2 bw = ((const uint2*)B2)[0];
    h2v d01 = BCH(aw.x) - BCH(bw.x);
    h2v d23 = BCH(aw.y) - BCH(bw.y);
    float dv00 = DOT2(d01, d01, DOT2(d23, d23, 0.0f));
    E1 = (l == 0) ? __builtin_exp2f(-dv00) : 0.0f;
  }

#define STEP(DM, ACT)                                                          \
  {                                                                            \
    float sA_ = rotup1f(E1) + E1;                                              \
    float sum_ = rotup1f(E2) + sA_;                                            \
    float pre_ = sum_ * (DM);                                                  \
    E2 = E1;                                                                   \
    E1 = (ACT) ? pre_ : 0.0f;                                                  \
  }

#define RENORM                                                                 \
  {                                                                            \
    float mx_ = fmaxf(E1, E2);                                                 \
    mx_ = fmaxf(mx_, __int_as_float(__builtin_amdgcn_update_dpp(               \
        0, __float_as_int(mx_), 0x111, 0xf, 0xf, false)));                     \
    mx_ = fmaxf(mx_, __int_as_float(__builtin_amdgcn_update_dpp(               \
        0, __float_as_int(mx_), 0x112, 0xf, 0xf, false)));                     \
    mx_ = fmaxf(mx_, __int_as_float(__builtin_amdgcn_update_dpp(               \
        0, __float_as_int(mx_), 0x114, 0xf, 0xf, false)));                     \
    mx_ = fmaxf(mx_, __int_as_float(__builtin_amdgcn_update_dpp(               \
        0, __float_as_int(mx_), 0x118, 0xf, 0xf, false)));                     \
    mx_ = fmaxf(mx_, __int_as_float(__builtin_amdgcn_update_dpp(               \
        0, __float_as_int(mx_), 0x142, 0xf, 0xf, false)));                     \
    mx_ = fmaxf(mx_, __int_as_float(__builtin_amdgcn_update_dpp(               \
        0, __float_as_int(mx_), 0x143, 0xf, 0xf, false)));                     \
    int c_ = 187 - ((__float_as_int(mx_) >> 23) & 0xFF);                       \
    c_ = rlanei(c_, 63);                                                       \
    E1 = __builtin_ldexpf(E1, c_);                                             \
    E2 = __builtin_ldexpf(E2, c_);                                             \
    S += c_;                                                                   \
  }

#define MACRO_P1                                                               \
  {                                                                            \
    unsigned wn_ = *wp; wp += 64;                                              \
    float dlo_ = __int_as_float(wc_ << 16);                                    \
    float dhi_ = __int_as_float(wc_ & 0xFFFF0000u);                            \
    STEP(dlo_, (int)l <= sd + 1)                                               \
    STEP(dhi_, (int)l <= sd + 2)                                               \
    sd += 2; wc_ = wn_;                                                        \
  }
#define MACRO_P2                                                               \
  {                                                                            \
    unsigned wn_ = *wp; wp += 64;                                              \
    t = (t + 63) & 63;                                                         \
    float dlo_ = __int_as_float(wc_ << 16);                                    \
    float dhi_ = __int_as_float(wc_ & 0xFFFF0000u);                            \
    STEP(dlo_, t <= 49)                                                        \
    STEP(dhi_, t <= 50)                                                        \
    wc_ = wn_;                                                                 \
  }
#define MACRO_P3                                                               \
  {                                                                            \
    unsigned wn_ = *wp; wp += 64;                                              \
    float dlo_ = __int_as_float(wc_ << 16);                                    \
    float dhi_ = __int_as_float(wc_ & 0xFFFF0000u);                            \
    t = (t + 63) & 63;                                                         \
    STEP(dlo_, t <= wA)                                                        \
    t = (t + 63) & 63;                                                         \
    STEP(dhi_, t <= wA - 1)                                                    \
    wA -= 2; wc_ = wn_;                                                        \
  }

  // P1: pairs 0..24 (d=1..50; ilo=0, act from scalar d)
  int sd = 0;
  for (int b = 0; b < 3; ++b) {
    #pragma clang loop unroll(disable)
    for (int q = 0; q < 8; ++q) { MACRO_P1 }
    RENORM
  }
  MACRO_P1   // p=24

  // P2: pairs 25..485 (ilo=p-24, t-update once per macro, widths 49/50)
  #pragma clang loop unroll(disable)
  for (int g = 0; g < 57; ++g) {
    #pragma clang loop unroll(disable)
    for (int q = 0; q < 8; ++q) { MACRO_P2 }
    RENORM
  }
  #pragma clang loop unroll(disable)
  for (int q = 0; q < 5; ++q) { MACRO_P2 }
  RENORM

  // P3: pairs 486..510 (d=973..1022; ilo=d-511, t-update per step)
  int wA = 49;   // width at d=973
  for (int b = 0; b < 3; ++b) {
    #pragma clang loop unroll(disable)
    for (int q = 0; q < 8; ++q) { MACRO_P3 }
    RENORM
  }
  MACRO_P3   // p=510 (d=1021,1022)

#undef MACRO_P1
#undef MACRO_P2
#undef MACRO_P3
#undef STEP
#undef RENORM

  // R[511,511] on lane 63 (t=0): stored E = true*2^S.
  if (l == 63) {
    ws[k] = -K2 * (__builtin_log2f(E1) - (float)S);
  }
}

__global__ void softdtw_combine_kernel(const float* __restrict__ ws,
                                       float* __restrict__ out) {
  int b = threadIdx.x;
  if (b < NB) out[b] = ws[b] - 0.5f * (ws[NB + b] + ws[2 * NB + b]);
}

extern "C" void kernel_launch(void* const* d_in, const int* in_sizes, int n_in,
                              void* d_out, int out_size, void* d_ws, size_t ws_size,
                              hipStream_t stream) {
  const float* x = (const float*)d_in[0];
  const float* y = (const float*)d_in[1];
  float* ws = (float*)d_ws;
  float* out = (float*)d_out;
  // >64KB dynamic LDS opt-in (not a stream op; capture-safe, idempotent).
  hipFuncSetAttribute((const void*)softdtw_fused,
                      hipFuncAttributeMaxDynamicSharedMemorySize, LDS_BYTES);
  softdtw_fused<<<3 * NB, 1024, LDS_BYTES, stream>>>(x, y, ws);
  softdtw_combine_kernel<<<1, 64, 0, stream>>>(ws, out);
}

// Round 16
// 47.441 us; speedup vs baseline: 2.4274x; 1.2779x over previous
//
#include <hip/hip_runtime.h>

static constexpr int NSEQ = 512;
static constexpr int NB = 32;
static constexpr int LDS_BYTES = 139264;   // 130816 dm (+pad) + A2 + B2

typedef _Float16 h2v __attribute__((ext_vector_type(2)));

// lane l <- lane (l-1)&63 : DPP wave rotate-right-by-1 (verified R5-R15).
// Must execute at full exec.
__device__ __forceinline__ float rotup1f(float v) {
  return __int_as_float(__builtin_amdgcn_update_dpp(
      0, __float_as_int(v), 0x13C, 0xf, 0xf, false));
}
__device__ __forceinline__ int rlanei(int v, int idx) {
  return __builtin_amdgcn_readlane(v, idx);
}
__device__ __forceinline__ h2v BCH(unsigned v) { return __builtin_bit_cast(h2v, v); }
__device__ __forceinline__ unsigned packh2s(float a, float b) {
  h2v v; v[0] = (_Float16)a; v[1] = (_Float16)b;
  return __builtin_bit_cast(unsigned, v);
}
// bf16 RNE (upper 16 bits of f32)
__device__ __forceinline__ unsigned bf16u(float f) {
  unsigned u = __float_as_uint(f);
  u += 0x7FFFu + ((u >> 16) & 1u);
  return u >> 16;
}
#if __has_builtin(__builtin_amdgcn_fdot2)
#define DOT2(a, b, c) __builtin_amdgcn_fdot2((a), (b), (c), false)
#else
__device__ __forceinline__ float dot2f(h2v a, h2v b, float c) {
  return c + (float)a[0] * (float)b[0] + (float)a[1] * (float)b[1];
}
#define DOT2(a, b, c) dot2f((a), (b), (c))
#endif

// R16 = R15 with the band logic moved INTO the dm table: stage 1 stores
// dm = 0 at lanes outside diagonal d's active window (inactive <=> E=0,
// and E1 = sum*dm, so masking is free). Stage 2 then has ZERO bookkeeping:
// no t, no cmp, no cndmask; one uniform loop of 511 pair-macros in 73
// groups of 7 with double-buffered register prefetch (ds_read offsets
// const-folded; ~400cy slack >> LDS latency). Renorm every 14 steps
// (R15-proven cadence). Step = 2 DPP-fused adds + 1 mul.
__global__ __launch_bounds__(1024) void softdtw_fused(
    const float* __restrict__ x, const float* __restrict__ y,
    float* __restrict__ ws)
{
  extern __shared__ unsigned char lds_raw[];
  unsigned* dmp = (unsigned*)lds_raw;                   // [511][64] u32
  unsigned* A2  = (unsigned*)(lds_raw + 131072);        // [512][2] f16x2
  unsigned* B2  = (unsigned*)(lds_raw + 135168);

  const int k = blockIdx.x;
  const int batch = k & (NB - 1);
  const int type = k >> 5;
  const float4* Aq = (const float4*)((type == 2 ? y : x) + (size_t)batch * NSEQ * 4);
  const float4* Bq = (const float4*)((type == 1 ? x : y) + (size_t)batch * NSEQ * 4);

  const int tid = threadIdx.x;
  const int l = tid & 63;
  const float SK1 = 0.8493216783f;      // sqrt(1/(2 ln2)); inputs prescaled
  const float K2 = 1.386294361119891f;  // gamma*ln2

  // ---- staging: prescaled f16 a,b into LDS ----
  {
    int idx = tid & 511;
    const float4* src = (tid < 512) ? Aq : Bq;
    float4 v = src[idx];
    unsigned w01 = packh2s(v.x * SK1, v.y * SK1);
    unsigned w23 = packh2s(v.z * SK1, v.w * SK1);
    unsigned* dst = (tid < 512) ? A2 : B2;
    dst[idx * 2] = w01;
    dst[idx * 2 + 1] = w23;
  }
  __syncthreads();

  // ---- stage 1: 16 waves fill dm[p][lane]; INACTIVE LANES GET EXACT 0 ----
  {
    const int wv = tid >> 6;
    #pragma clang loop unroll(disable)
    for (int q = 0; q < 32; ++q) {
      int p = wv * 32 + q;
      if (p > 510) break;
      float dmv0, dmv1;
      #pragma unroll
      for (int s = 0; s < 2; ++s) {
        int d = 2 * p + 1 + s;
        int ilo = max(max(0, d - (NSEQ - 1)), max(0, d - 49) >> 1);
        int ihi = min(min(NSEQ - 1, d), (d + 50) >> 1);
        int tt = (l - ilo) & 63;
        int i0 = ilo + tt;                 // unclamped row for act test
        int i = min(i0, NSEQ - 1);
        int j = min(max(d - i0, 0), NSEQ - 1);
        uint2 aw = ((const uint2*)A2)[i];
        uint2 bw = ((const uint2*)B2)[j];
        h2v d01 = BCH(aw.x) - BCH(bw.x);
        h2v d23 = BCH(aw.y) - BCH(bw.y);
        float dvv = DOT2(d01, d01, DOT2(d23, d23, 0.0f));
        float dmv = (i0 <= ihi) ? __builtin_exp2f(-dvv) : 0.0f;
        if (s == 0) dmv0 = dmv; else dmv1 = dmv;
      }
      dmp[p * 64 + l] = bf16u(dmv0) | (bf16u(dmv1) << 16);   // bf16x2 RNE
    }
  }
  __syncthreads();
  if (tid >= 64) return;

  // ---- stage 2: single-wave DP, zero band bookkeeping ----
  const unsigned* wp = dmp + l;
  unsigned c0 = wp[0], c1 = wp[64], c2 = wp[128], c3 = wp[192],
           c4 = wp[256], c5 = wp[320], c6 = wp[384];   // group 0 preload
  unsigned n0, n1, n2, n3, n4, n5, n6;
  int S = 0;

  // seed d=0: E1 = exp2(-dist²(0,0)) on lane 0; E2 (diag -1) = 0 = BIG.
  float E1, E2 = 0.0f;
  {
    uint2 aw = ((const uint2*)A2)[0];
    uint2 bw = ((const uint2*)B2)[0];
    h2v d01 = BCH(aw.x) - BCH(bw.x);
    h2v d23 = BCH(aw.y) - BCH(bw.y);
    float dv00 = DOT2(d01, d01, DOT2(d23, d23, 0.0f));
    E1 = (l == 0) ? __builtin_exp2f(-dv00) : 0.0f;
  }

#define STEP(DM)                                                               \
  {                                                                            \
    float sA_ = rotup1f(E1) + E1;                                              \
    float sum_ = rotup1f(E2) + sA_;                                            \
    E2 = E1;                                                                   \
    E1 = sum_ * (DM);                                                          \
  }
#define MAC(W)                                                                 \
  {                                                                            \
    float dlo_ = __int_as_float((W) << 16);                                    \
    float dhi_ = __int_as_float((W) & 0xFFFF0000u);                            \
    STEP(dlo_) STEP(dhi_)                                                      \
  }
#define RENORM                                                                 \
  {                                                                            \
    float mx_ = fmaxf(E1, E2);                                                 \
    mx_ = fmaxf(mx_, __int_as_float(__builtin_amdgcn_update_dpp(               \
        0, __float_as_int(mx_), 0x111, 0xf, 0xf, false)));                     \
    mx_ = fmaxf(mx_, __int_as_float(__builtin_amdgcn_update_dpp(               \
        0, __float_as_int(mx_), 0x112, 0xf, 0xf, false)));                     \
    mx_ = fmaxf(mx_, __int_as_float(__builtin_amdgcn_update_dpp(               \
        0, __float_as_int(mx_), 0x114, 0xf, 0xf, false)));                     \
    mx_ = fmaxf(mx_, __int_as_float(__builtin_amdgcn_update_dpp(               \
        0, __float_as_int(mx_), 0x118, 0xf, 0xf, false)));                     \
    mx_ = fmaxf(mx_, __int_as_float(__builtin_amdgcn_update_dpp(               \
        0, __float_as_int(mx_), 0x142, 0xf, 0xf, false)));                     \
    mx_ = fmaxf(mx_, __int_as_float(__builtin_amdgcn_update_dpp(               \
        0, __float_as_int(mx_), 0x143, 0xf, 0xf, false)));                     \
    int c_ = 187 - ((__float_as_int(mx_) >> 23) & 0xFF);                       \
    c_ = rlanei(c_, 63);                                                       \
    E1 = __builtin_ldexpf(E1, c_);                                             \
    E2 = __builtin_ldexpf(E2, c_);                                             \
    S += c_;                                                                   \
  }
// One group: consume 7 pairs (14 diagonals), prefetch next group's 7 words.
// Final group's prefetch overruns into A2 region: in-bounds, never used.
#define GROUP(C0, C1, C2, C3, C4, C5, C6, N0, N1, N2, N3, N4, N5, N6)          \
  {                                                                            \
    N0 = wp[448]; N1 = wp[512]; N2 = wp[576]; N3 = wp[640];                    \
    N4 = wp[704]; N5 = wp[768]; N6 = wp[832];                                  \
    MAC(C0) MAC(C1) MAC(C2) MAC(C3) MAC(C4) MAC(C5) MAC(C6)                    \
    RENORM                                                                     \
    wp += 448;                                                                 \
  }

  // 73 groups x 7 pairs = 511 pairs = diagonals 1..1022.
  #pragma clang loop unroll(disable)
  for (int it = 0; it < 36; ++it) {
    GROUP(c0, c1, c2, c3, c4, c5, c6, n0, n1, n2, n3, n4, n5, n6)
    GROUP(n0, n1, n2, n3, n4, n5, n6, c0, c1, c2, c3, c4, c5, c6)
  }
  GROUP(c0, c1, c2, c3, c4, c5, c6, n0, n1, n2, n3, n4, n5, n6)   // group 72

#undef GROUP
#undef RENORM
#undef MAC
#undef STEP

  // R[511,511] lives on lane 511&63 = 63. Stored E = true*2^S.
  if (l == 63) {
    ws[k] = -K2 * (__builtin_log2f(E1) - (float)S);
  }
}

__global__ void softdtw_combine_kernel(const float* __restrict__ ws,
                                       float* __restrict__ out) {
  int b = threadIdx.x;
  if (b < NB) out[b] = ws[b] - 0.5f * (ws[NB + b] + ws[2 * NB + b]);
}

extern "C" void kernel_launch(void* const* d_in, const int* in_sizes, int n_in,
                              void* d_out, int out_size, void* d_ws, size_t ws_size,
                              hipStream_t stream) {
  const float* x = (const float*)d_in[0];
  const float* y = (const float*)d_in[1];
  float* ws = (float*)d_ws;
  float* out = (float*)d_out;
  // >64KB dynamic LDS opt-in (not a stream op; capture-safe, idempotent).
  hipFuncSetAttribute((const void*)softdtw_fused,
                      hipFuncAttributeMaxDynamicSharedMemorySize, LDS_BYTES);
  softdtw_fused<<<3 * NB, 1024, LDS_BYTES, stream>>>(x, y, ws);
  softdtw_combine_kernel<<<1, 64, 0, stream>>>(ws, out);
}

// Round 17
// 30.535 us; speedup vs baseline: 3.7714x; 1.5537x over previous
//
#include <hip/hip_runtime.h>

static constexpr int NSEQ = 512;
static constexpr int NB = 32;
static constexpr int LDS_BYTES = 140288;  // 131072 dm + 4096 A2 + 5120 B2pad

typedef _Float16 h2v __attribute__((ext_vector_type(2)));

// lane l <- lane (l-1)&63 : DPP wave rotate-right-by-1 (verified R5-R16).
// Must execute at full exec.
__device__ __forceinline__ float rotup1f(float v) {
  return __int_as_float(__builtin_amdgcn_update_dpp(
      0, __float_as_int(v), 0x13C, 0xf, 0xf, false));
}
__device__ __forceinline__ int rlanei(int v, int idx) {
  return __builtin_amdgcn_readlane(v, idx);
}
__device__ __forceinline__ h2v BCH(unsigned v) { return __builtin_bit_cast(h2v, v); }
__device__ __forceinline__ unsigned packh2s(float a, float b) {
  h2v v; v[0] = (_Float16)a; v[1] = (_Float16)b;
  return __builtin_bit_cast(unsigned, v);
}
#if __has_builtin(__builtin_amdgcn_fdot2)
#define DOT2(a, b, c) __builtin_amdgcn_fdot2((a), (b), (c), false)
#else
__device__ __forceinline__ float dot2f(h2v a, h2v b, float c) {
  return c + (float)a[0] * (float)b[0] + (float)a[1] * (float)b[1];
}
#define DOT2(a, b, c) dot2f((a), (b), (c))
#endif
// v_cvt_pk_bf16_f32: d = {hi: bf16(s1), lo: bf16(s0)} (gfx950; per guide m214v22)
__device__ __forceinline__ unsigned cvtpk_bf16(float lo, float hi) {
  unsigned r;
  asm("v_cvt_pk_bf16_f32 %0, %1, %2" : "=v"(r) : "v"(lo), "v"(hi));
  return r;
}

// R17: both stages slimmed under the measured 6.5 cy/inst per-SIMD issue law.
// Stage 1 (i-major): lane=row i (a[i] in regs), iterate band offset; b reads
// are 2x ds_read_b64 off one walking address; OOB cells -> 0 via +inf b-pads
// (dist=inf, exp2(-inf)=0); pack 2 diagonals with one v_cvt_pk_bf16_f32;
// OOB words -> scratch row 511; dmp pre-zeroed so inactive words are 0
// (R16's 0==BIG masking). Stage 2: rotated state (r1=R E1, r2=R E2):
// step = {sum=E1+r1+r2; E1'=sum*dm; r1'=R E1'} = 4 inst, 1 DPP; renorm
// every 28 steps (growth<=3^28 from 2^60 => <2^105, safe; underflow=BIG ok).
__global__ __launch_bounds__(1024) void softdtw_fused(
    const float* __restrict__ x, const float* __restrict__ y,
    float* __restrict__ ws)
{
  extern __shared__ unsigned char lds_raw[];
  unsigned* dmp = (unsigned*)lds_raw;                 // [512][64] u32 (row 511 = scratch)
  uint2* A2  = (uint2*)(lds_raw + 131072);            // [512] f16x4
  uint2* B2p = (uint2*)(lds_raw + 135168);            // [640]; b[j] at index 64+j

  const int k = blockIdx.x;
  const int batch = k & (NB - 1);
  const int type = k >> 5;
  const float4* Aq = (const float4*)((type == 2 ? y : x) + (size_t)batch * NSEQ * 4);
  const float4* Bq = (const float4*)((type == 1 ? x : y) + (size_t)batch * NSEQ * 4);

  const int tid = threadIdx.x;
  const int l = tid & 63;
  const float SK1 = 0.8493216783f;      // sqrt(1/(2 ln2)); inputs prescaled
  const float K2 = 1.386294361119891f;  // gamma*ln2

  // ---- staging: zero dm region; prescaled f16 a,b into LDS; inf pads ----
  {
    uint4* z = (uint4*)lds_raw;         // 8192 uint4 = 131072 B
    #pragma unroll
    for (int q = 0; q < 8; ++q) z[tid + q * 1024] = make_uint4(0u, 0u, 0u, 0u);
    int idx = tid & 511;
    const float4* src = (tid < 512) ? Aq : Bq;
    float4 v = src[idx];
    unsigned w01 = packh2s(v.x * SK1, v.y * SK1);
    unsigned w23 = packh2s(v.z * SK1, v.w * SK1);
    if (tid < 512) A2[idx] = make_uint2(w01, w23);
    else           B2p[64 + idx] = make_uint2(w01, w23);
    if (tid < 64)       B2p[tid] = make_uint2(0x7C007C00u, 0x7C007C00u);
    else if (tid < 128) B2p[512 + tid] = make_uint2(0x7C007C00u, 0x7C007C00u);
  }
  __syncthreads();

  // ---- stage 1 (i-major): wave wv = (bi, h); i = 64*bi + l.
  // Word q holds diagonals d=2p+1 (lo, off=2q+1), d=2p+2 (hi, off=2q+2), p=i+q.
  // h=0: special q=-26 (lo is off=-51: OOB => 0) then q=-25..-1; h=1: q=0..24.
  {
    const int wv = tid >> 6;
    const int bi = wv >> 1;
    const int h  = wv & 1;
    const int i  = bi * 64 + l;
    uint2 aw = A2[i];
    h2v a01 = BCH(aw.x), a23 = BCH(aw.y);

    if (h == 0) {
      uint2 bw = B2p[64 + i - 50];            // j = i-50 (idx >= 14)
      h2v d01 = a01 - BCH(bw.x), d23 = a23 - BCH(bw.y);
      float dvv = DOT2(d01, d01, DOT2(d23, d23, 0.0f));
      unsigned w = cvtpk_bf16(0.0f, __builtin_exp2f(-dvv));
      unsigned p = (unsigned)(i - 26);
      if (p > 510u) p = 511u;                 // scratch row (never read)
      dmp[p * 64 + l] = w;
    }
    const int q0 = h ? 0 : -25;
    #pragma unroll 5
    for (int n = 0; n < 25; ++n) {
      int q = q0 + n;
      const uint2* bp = &B2p[64 + i + 2 * q + 1];   // idx in [15, 625] ✓
      uint2 blo = bp[0];
      uint2 bhi = bp[1];
      h2v e01 = a01 - BCH(blo.x), e23 = a23 - BCH(blo.y);
      float dvl = DOT2(e01, e01, DOT2(e23, e23, 0.0f));
      h2v f01 = a01 - BCH(bhi.x), f23 = a23 - BCH(bhi.y);
      float dvh = DOT2(f01, f01, DOT2(f23, f23, 0.0f));
      unsigned w = cvtpk_bf16(__builtin_exp2f(-dvl), __builtin_exp2f(-dvh));
      unsigned p = (unsigned)(i + q);
      if (p > 510u) p = 511u;
      dmp[p * 64 + l] = w;
    }
  }
  __syncthreads();
  if (tid >= 64) return;

  // ---- stage 2: single-wave DP, rotated state ----
  const unsigned* wp = dmp + l;
  unsigned c0 = wp[0],   c1 = wp[64],  c2 = wp[128], c3 = wp[192],
           c4 = wp[256], c5 = wp[320], c6 = wp[384], c7 = wp[448],
           c8 = wp[512], c9 = wp[576], c10 = wp[640], c11 = wp[704],
           c12 = wp[768], c13 = wp[832];
  unsigned n0, n1, n2, n3, n4, n5, n6, n7, n8, n9, n10, n11, n12, n13;
  int S = 0;

  // seed d=0 on lane 0; r2 (diag -1) = 0 = BIG.
  float E1, r1, r2 = 0.0f;
  {
    uint2 aw = A2[0];
    uint2 bw = B2p[64];
    h2v d01 = BCH(aw.x) - BCH(bw.x);
    h2v d23 = BCH(aw.y) - BCH(bw.y);
    float dv00 = DOT2(d01, d01, DOT2(d23, d23, 0.0f));
    E1 = (l == 0) ? __builtin_exp2f(-dv00) : 0.0f;
  }
  r1 = rotup1f(E1);

#define MAC(W)                                                                 \
  {                                                                            \
    float dlo_ = __int_as_float((W) << 16);                                    \
    float dhi_ = __int_as_float((W) & 0xFFFF0000u);                            \
    float sA_ = E1 + r1; sA_ += r2;                                            \
    float eA_ = sA_ * dlo_;                                                    \
    float rA_ = rotup1f(eA_);                                                  \
    float sB_ = eA_ + rA_; sB_ += r1;                                          \
    float eB_ = sB_ * dhi_;                                                    \
    float rB_ = rotup1f(eB_);                                                  \
    E1 = eB_; r2 = rA_; r1 = rB_;                                              \
  }
#define RENORM                                                                 \
  {                                                                            \
    float mx_ = fmaxf(E1, r2);                                                 \
    mx_ = fmaxf(mx_, __int_as_float(__builtin_amdgcn_update_dpp(               \
        0, __float_as_int(mx_), 0x111, 0xf, 0xf, false)));                     \
    mx_ = fmaxf(mx_, __int_as_float(__builtin_amdgcn_update_dpp(               \
        0, __float_as_int(mx_), 0x112, 0xf, 0xf, false)));                     \
    mx_ = fmaxf(mx_, __int_as_float(__builtin_amdgcn_update_dpp(               \
        0, __float_as_int(mx_), 0x114, 0xf, 0xf, false)));                     \
    mx_ = fmaxf(mx_, __int_as_float(__builtin_amdgcn_update_dpp(               \
        0, __float_as_int(mx_), 0x118, 0xf, 0xf, false)));                     \
    mx_ = fmaxf(mx_, __int_as_float(__builtin_amdgcn_update_dpp(               \
        0, __float_as_int(mx_), 0x142, 0xf, 0xf, false)));                     \
    mx_ = fmaxf(mx_, __int_as_float(__builtin_amdgcn_update_dpp(               \
        0, __float_as_int(mx_), 0x143, 0xf, 0xf, false)));                     \
    int c_ = 187 - ((__float_as_int(mx_) >> 23) & 0xFF);                       \
    c_ = rlanei(c_, 63);                                                       \
    E1 = __builtin_ldexpf(E1, c_);                                             \
    r1 = __builtin_ldexpf(r1, c_);                                             \
    r2 = __builtin_ldexpf(r2, c_);                                             \
    S += c_;                                                                   \
  }
// One group: consume 14 words (28 diagonals), prefetch next 14, renorm once.
// Final groups' prefetch overruns into A2/B2 region: in-bounds, unused.
#define GROUP(C0,C1,C2,C3,C4,C5,C6,C7,C8,C9,C10,C11,C12,C13,                   \
              N0,N1,N2,N3,N4,N5,N6,N7,N8,N9,N10,N11,N12,N13)                   \
  {                                                                            \
    N0 = wp[896];  N1 = wp[960];  N2 = wp[1024]; N3 = wp[1088];                \
    N4 = wp[1152]; N5 = wp[1216]; N6 = wp[1280]; N7 = wp[1344];                \
    N8 = wp[1408]; N9 = wp[1472]; N10 = wp[1536]; N11 = wp[1600];              \
    N12 = wp[1664]; N13 = wp[1728];                                            \
    MAC(C0) MAC(C1) MAC(C2) MAC(C3) MAC(C4) MAC(C5) MAC(C6)                    \
    MAC(C7) MAC(C8) MAC(C9) MAC(C10) MAC(C11) MAC(C12) MAC(C13)                \
    RENORM                                                                     \
    wp += 896;                                                                 \
  }

  // 36 groups x 14 words + 7-word tail = 511 pairs = diagonals 1..1022.
  #pragma clang loop unroll(disable)
  for (int it = 0; it < 18; ++it) {
    GROUP(c0,c1,c2,c3,c4,c5,c6,c7,c8,c9,c10,c11,c12,c13,
          n0,n1,n2,n3,n4,n5,n6,n7,n8,n9,n10,n11,n12,n13)
    GROUP(n0,n1,n2,n3,n4,n5,n6,n7,n8,n9,n10,n11,n12,n13,
          c0,c1,c2,c3,c4,c5,c6,c7,c8,c9,c10,c11,c12,c13)
  }
  // tail: words 504..510 (in c0..c6 from the last prefetch)
  MAC(c0) MAC(c1) MAC(c2) MAC(c3) MAC(c4) MAC(c5) MAC(c6)

#undef GROUP
#undef RENORM
#undef MAC

  // R[511,511] lives on lane 511&63 = 63. Stored E = true*2^S.
  if (l == 63) {
    ws[k] = -K2 * (__builtin_log2f(E1) - (float)S);
  }
}

__global__ void softdtw_combine_kernel(const float* __restrict__ ws,
                                       float* __restrict__ out) {
  int b = threadIdx.x;
  if (b < NB) out[b] = ws[b] - 0.5f * (ws[NB + b] + ws[2 * NB + b]);
}

extern "C" void kernel_launch(void* const* d_in, const int* in_sizes, int n_in,
                              void* d_out, int out_size, void* d_ws, size_t ws_size,
                              hipStream_t stream) {
  const float* x = (const float*)d_in[0];
  const float* y = (const float*)d_in[1];
  float* ws = (float*)d_ws;
  float* out = (float*)d_out;
  // >64KB dynamic LDS opt-in (not a stream op; capture-safe, idempotent).
  hipFuncSetAttribute((const void*)softdtw_fused,
                      hipFuncAttributeMaxDynamicSharedMemorySize, LDS_BYTES);
  softdtw_fused<<<3 * NB, 1024, LDS_BYTES, stream>>>(x, y, ws);
  softdtw_combine_kernel<<<1, 64, 0, stream>>>(ws, out);
}